// Round 1
// baseline (364.158 us; speedup 1.0000x reference)
//
#include <hip/hip_runtime.h>
#include <hip/hip_bf16.h>

#define NPTS 262144
#define MRB  131072
#define KOFF 9

typedef __attribute__((ext_vector_type(8))) short short8;
typedef __attribute__((ext_vector_type(4))) float f32x4;

__device__ __forceinline__ short f2bf(float f) {
    __hip_bfloat16 h = __float2bfloat16(f);
    return __builtin_bit_cast(short, h);
}

__device__ __forceinline__ void atomic_add_f32(float* p, float v) {
    __hip_atomic_fetch_add(p, v, __ATOMIC_RELAXED, __HIP_MEMORY_SCOPE_AGENT);
}

// d_out layout (all read back as fp32):
//   [0, NPTS*3)            coords converted to float
//   [NPTS*3, NPTS*3+NPTS*64) output features, initialized to bias then atomically accumulated
__global__ __launch_bounds__(256) void init_kernel(const int* __restrict__ coords,
                                                   const float* __restrict__ bias,
                                                   float* __restrict__ out) {
    const int tid = blockIdx.x * blockDim.x + threadIdx.x;
    const int nc4 = (NPTS * 3) / 4;        // int4/float4 count of coords region
    const int nf4 = (NPTS * 64) / 4;       // float4 count of feature region
    for (int i = tid; i < nc4 + nf4; i += gridDim.x * blockDim.x) {
        if (i < nc4) {
            int4 c = ((const int4*)coords)[i];
            float4 f;
            f.x = (float)c.x; f.y = (float)c.y; f.z = (float)c.z; f.w = (float)c.w;
            ((float4*)out)[i] = f;
        } else {
            int j = i - nc4;               // float4 index within feature region
            float4 b = ((const float4*)bias)[j & 15];   // 16 float4 per 64-ch row
            ((float4*)(out + (size_t)NPTS * 3))[j] = b;
        }
    }
}

// One wave computes a 16-entry x 64-cout tile for one kernel offset k:
//   A [16 x 64] = gathered feat rows (bf16), B [64 x 64] = weight[k] (bf16),
//   8x mfma_f32_16x16x32_bf16 (4 n-tiles x 2 k-tiles), fp32 acc, atomic scatter.
// Fragment layouts (gfx950, verified in ladder m89/m97):
//   A: row = lane&15, k = kk*32 + 8*(lane>>4) + j (j=0..7 contiguous)
//   B: col = lane&15 (+16*nt), same k mapping
//   D: col = lane&15 (+16*nt), row = 4*(lane>>4) + r
__global__ __launch_bounds__(256) void conv_main(const float* __restrict__ feats,
                                                 const int*   __restrict__ in_rows,
                                                 const int*   __restrict__ out_rows,
                                                 const float* __restrict__ weight,
                                                 float*       __restrict__ out) {
    const int lane = threadIdx.x & 63;
    const int wv   = threadIdx.x >> 6;
    const int lrow = lane & 15;
    const int lhi  = lane >> 4;
    const int BPK  = MRB / 64;                    // 2048 blocks per offset
    const int k    = blockIdx.x / BPK;
    const int mb   = (blockIdx.x % BPK) * 64 + wv * 16;

    // ---- B fragments: weight[k] -> bf16, kept in registers (L1/L2-hot reads) ----
    const float* Wk = weight + k * 64 * 64;
    short8 bfrag[2][4];
#pragma unroll
    for (int kk = 0; kk < 2; ++kk)
#pragma unroll
        for (int nt = 0; nt < 4; ++nt)
#pragma unroll
            for (int j = 0; j < 8; ++j)
                bfrag[kk][nt][j] = f2bf(Wk[(kk * 32 + lhi * 8 + j) * 64 + nt * 16 + lrow]);

    // ---- gather A: 16 feat rows, each lane reads its 8-contiguous-k chunk ----
    const int arow = in_rows[k * MRB + mb + lrow];
    const float* ap = feats + (long)arow * 64 + lhi * 8;

    f32x4 acc[4] = {};
#pragma unroll
    for (int kk = 0; kk < 2; ++kk) {
        float4 f0 = *(const float4*)(ap + kk * 32);
        float4 f1 = *(const float4*)(ap + kk * 32 + 4);
        short8 afrag;
        afrag[0] = f2bf(f0.x); afrag[1] = f2bf(f0.y);
        afrag[2] = f2bf(f0.z); afrag[3] = f2bf(f0.w);
        afrag[4] = f2bf(f1.x); afrag[5] = f2bf(f1.y);
        afrag[6] = f2bf(f1.z); afrag[7] = f2bf(f1.w);
#pragma unroll
        for (int nt = 0; nt < 4; ++nt)
            acc[nt] = __builtin_amdgcn_mfma_f32_16x16x32_bf16(afrag, bfrag[kk][nt], acc[nt], 0, 0, 0);
    }

    // ---- scatter-add: entry = 4*lhi + r, col = 16*nt + lrow ----
    const int ob = k * MRB + mb + lhi * 4;
#pragma unroll
    for (int r = 0; r < 4; ++r) {
        const int orow = out_rows[ob + r];
        float* op = out + (long)orow * 64 + lrow;
#pragma unroll
        for (int nt = 0; nt < 4; ++nt)
            atomic_add_f32(op + nt * 16, acc[nt][r]);
    }
}

extern "C" void kernel_launch(void* const* d_in, const int* in_sizes, int n_in,
                              void* d_out, int out_size, void* d_ws, size_t ws_size,
                              hipStream_t stream) {
    const int*   coords   = (const int*)  d_in[0];
    const float* feats    = (const float*)d_in[1];
    const int*   in_rows  = (const int*)  d_in[2];
    const int*   out_rows = (const int*)  d_in[3];
    const float* weight   = (const float*)d_in[4];
    const float* bias     = (const float*)d_in[5];
    float* out = (float*)d_out;

    hipLaunchKernelGGL(init_kernel, dim3(2048), dim3(256), 0, stream, coords, bias, out);
    hipLaunchKernelGGL(conv_main, dim3(KOFF * (MRB / 64)), dim3(256), 0, stream,
                       feats, in_rows, out_rows, weight, out + (size_t)NPTS * 3);
}